// Round 1
// baseline (1190.743 us; speedup 1.0000x reference)
//
#include <hip/hip_runtime.h>

#define NBINS 31
#define PITCH 260   // 260*4 = 1040 bytes per row: 16B-aligned rows, bank = (4b+tid)%32 -> <=2-way (free)

struct Ws {
    unsigned int minkey;
    unsigned int maxkey;
    unsigned long long nz;
    double sum;
    double ss;
    unsigned int counts[NBINS];
};

// Monotone float -> uint key (order-preserving over all finite floats incl. -0/+0).
__device__ __forceinline__ unsigned int fkey(float f) {
    unsigned int u = __float_as_uint(f);
    return (u & 0x80000000u) ? ~u : (u | 0x80000000u);
}
__device__ __forceinline__ float funkey(unsigned int k) {
    return (k & 0x80000000u) ? __uint_as_float(k & 0x7FFFFFFFu)
                             : __uint_as_float(~k);
}

// Must match the edges we emit in k_final exactly: mul then add, no FMA contraction.
__device__ __forceinline__ float edge_at(float mn, float step, int i) {
    return __fadd_rn(mn, __fmul_rn((float)i, step));
}

__global__ void k_init(Ws* ws) {
    int t = threadIdx.x;
    if (t == 0) {
        ws->minkey = 0xFFFFFFFFu;
        ws->maxkey = 0u;
        ws->nz = 0ull;
        ws->sum = 0.0;
        ws->ss = 0.0;
    }
    if (t < NBINS) ws->counts[t] = 0u;
}

__global__ void __launch_bounds__(256) k_reduce(const float* __restrict__ x, long long n, Ws* ws) {
    long long n4 = n >> 2;
    const float4* __restrict__ x4 = (const float4*)x;
    float mn = INFINITY, mx = -INFINITY;
    float s = 0.f, ss = 0.f;
    unsigned int nz = 0u;

    long long i = (long long)blockIdx.x * blockDim.x + threadIdx.x;
    long long stride = (long long)gridDim.x * blockDim.x;
    for (; i < n4; i += stride) {
        float4 v = x4[i];
        mn = fminf(mn, fminf(fminf(v.x, v.y), fminf(v.z, v.w)));
        mx = fmaxf(mx, fmaxf(fmaxf(v.x, v.y), fmaxf(v.z, v.w)));
        s  += (v.x + v.y) + (v.z + v.w);
        ss += (v.x * v.x + v.y * v.y) + (v.z * v.z + v.w * v.w);
        nz += (v.x != 0.f) + (v.y != 0.f) + (v.z != 0.f) + (v.w != 0.f);
    }
    // tail (n not multiple of 4)
    if (blockIdx.x == 0 && threadIdx.x < (int)(n & 3)) {
        float v = x[(n4 << 2) + threadIdx.x];
        mn = fminf(mn, v);
        mx = fmaxf(mx, v);
        s += v;
        ss += v * v;
        nz += (v != 0.f);
    }

    // wave(64) reduce
    #pragma unroll
    for (int off = 32; off > 0; off >>= 1) {
        mn = fminf(mn, __shfl_down(mn, off));
        mx = fmaxf(mx, __shfl_down(mx, off));
        s  += __shfl_down(s, off);
        ss += __shfl_down(ss, off);
        nz += __shfl_down(nz, off);
    }
    if ((threadIdx.x & 63) == 0) {
        atomicMin(&ws->minkey, fkey(mn));
        atomicMax(&ws->maxkey, fkey(mx));
        atomicAdd(&ws->sum, (double)s);
        atomicAdd(&ws->ss, (double)ss);
        atomicAdd(&ws->nz, (unsigned long long)nz);
    }
}

__device__ __forceinline__ void bump(float v, float mn, float step, float inv,
                                     unsigned int* hist, int tid) {
    int b = (int)((v - mn) * inv);
    b = b < 0 ? 0 : (b > NBINS - 1 ? NBINS - 1 : b);
    // exact fixup vs the emitted edges (searchsorted side="right" - 1, last bin inclusive)
    while (b > 0 && v < edge_at(mn, step, b)) --b;
    while (b < NBINS - 1 && v >= edge_at(mn, step, b + 1)) ++b;
    atomicAdd(&hist[b * PITCH + tid], 1u);
}

__global__ void __launch_bounds__(256) k_hist(const float* __restrict__ x, long long n, Ws* ws) {
    __shared__ unsigned int hist[NBINS * PITCH];
    int tid = threadIdx.x;
    for (int j = tid; j < NBINS * PITCH; j += 256) hist[j] = 0u;

    float mn = funkey(ws->minkey);
    float mx = funkey(ws->maxkey);
    float step = (mx - mn) / 31.0f;
    float inv  = 31.0f / (mx - mn);
    __syncthreads();

    long long n4 = n >> 2;
    const float4* __restrict__ x4 = (const float4*)x;
    long long i = (long long)blockIdx.x * blockDim.x + threadIdx.x;
    long long stride = (long long)gridDim.x * blockDim.x;
    for (; i < n4; i += stride) {
        float4 v = x4[i];
        bump(v.x, mn, step, inv, hist, tid);
        bump(v.y, mn, step, inv, hist, tid);
        bump(v.z, mn, step, inv, hist, tid);
        bump(v.w, mn, step, inv, hist, tid);
    }
    if (blockIdx.x == 0 && tid < (int)(n & 3)) {
        bump(x[(n4 << 2) + tid], mn, step, inv, hist, tid);
    }
    __syncthreads();

    // block reduce: wave w handles bins b = w, w+4, ... ; each lane sums 4 contiguous entries
    int w = tid >> 6, lane = tid & 63;
    for (int b = w; b < NBINS; b += 4) {
        const unsigned int* row = &hist[b * PITCH];
        uint4 q = *(const uint4*)(row + (lane << 2));  // rows are 16B-aligned (PITCH*4 % 16 == 0)
        unsigned int sv = q.x + q.y + q.z + q.w;
        #pragma unroll
        for (int off = 32; off > 0; off >>= 1) sv += __shfl_down(sv, off);
        if (lane == 0) atomicAdd(&ws->counts[b], sv);
    }
}

__global__ void k_final(const Ws* __restrict__ ws, float* __restrict__ out, long long n) {
    int t = threadIdx.x;
    float mn = funkey(ws->minkey);
    float mx = funkey(ws->maxkey);
    float step = (mx - mn) / 31.0f;
    if (t == 0) {
        out[0] = mn;
        out[1] = mx;
        out[2] = (float)n;                 // num (2^26 is fp32-exact)
        out[3] = (float)ws->nz;            // nonzero_count
        out[4] = (float)ws->sum;           // s
        out[5] = (float)ws->ss;            // ss
    }
    if (t < NBINS) out[6 + t] = (float)ws->counts[t];
    if (t < NBINS + 1) out[6 + NBINS + t] = (t == NBINS) ? mx : edge_at(mn, step, t);
}

extern "C" void kernel_launch(void* const* d_in, const int* in_sizes, int n_in,
                              void* d_out, int out_size, void* d_ws, size_t ws_size,
                              hipStream_t stream) {
    const float* x = (const float*)d_in[0];
    long long n = (long long)in_sizes[0];
    Ws* ws = (Ws*)d_ws;
    float* out = (float*)d_out;

    k_init<<<dim3(1), dim3(64), 0, stream>>>(ws);
    k_reduce<<<dim3(2048), dim3(256), 0, stream>>>(x, n, ws);
    k_hist<<<dim3(1280), dim3(256), 0, stream>>>(x, n, ws);
    k_final<<<dim3(1), dim3(128), 0, stream>>>(ws, out, n);
}

// Round 2
// 539.491 us; speedup vs baseline: 2.2072x; 2.2072x over previous
//
#include <hip/hip_runtime.h>

#define NBINS 31
#define NB1 2048   // k_reduce grid
#define NB2 1024   // k_hist grid (32KB LDS/block -> 4 blocks/CU, fully resident)
#define PITCH 260  // words per hist row: 16B-aligned rows, bank=(4b+tid)%32 -> <=2-way (free)

struct Partial {                       // 32 B, one per k_reduce block
    unsigned int mnk, mxk, nz, pad;
    double s, ss;
};
struct Finals {
    unsigned int minkey, maxkey;
    unsigned long long nz;
    double sum, ss;
};
// ws layout:
//   [0, NB1*32)                  Partial part[NB1]            (64 KB)
//   [OFF_F, OFF_F+64)            Finals                       (64 B)
//   [OFF_C, OFF_C+NBINS*NB2*4)   unsigned cpart[NBINS][NB2]   (124 KB)
#define OFF_F (NB1 * 32)
#define OFF_C (OFF_F + 64)

__device__ __forceinline__ unsigned int fkey(float f) {
    unsigned int u = __float_as_uint(f);
    return (u & 0x80000000u) ? ~u : (u | 0x80000000u);
}
__device__ __forceinline__ float funkey(unsigned int k) {
    return (k & 0x80000000u) ? __uint_as_float(k & 0x7FFFFFFFu)
                             : __uint_as_float(~k);
}
// Must match edges emitted in k_final exactly: mul then add, no FMA contraction.
__device__ __forceinline__ float edge_at(float mn, float step, int i) {
    return __fadd_rn(mn, __fmul_rn((float)i, step));
}

__device__ __forceinline__ void acc4(float4 v, float& mn, float& mx, float& s, float& ss,
                                     unsigned int& nz) {
    mn = fminf(mn, fminf(fminf(v.x, v.y), fminf(v.z, v.w)));
    mx = fmaxf(mx, fmaxf(fmaxf(v.x, v.y), fmaxf(v.z, v.w)));
    s  += (v.x + v.y) + (v.z + v.w);
    ss += (v.x * v.x + v.y * v.y) + (v.z * v.z + v.w * v.w);
    nz += (v.x != 0.f) + (v.y != 0.f) + (v.z != 0.f) + (v.w != 0.f);
}

__global__ void __launch_bounds__(256) k_reduce(const float* __restrict__ x, long long n,
                                                Partial* __restrict__ part) {
    long long n4 = n >> 2;
    const float4* __restrict__ x4 = (const float4*)x;
    float mn = INFINITY, mx = -INFINITY, s = 0.f, ss = 0.f;
    unsigned int nz = 0u;

    long long stride = (long long)gridDim.x * blockDim.x;
    long long i = (long long)blockIdx.x * blockDim.x + threadIdx.x;
    for (; i + 3 * stride < n4; i += 4 * stride) {       // 4 independent loads in flight
        float4 a = x4[i], b = x4[i + stride], c = x4[i + 2 * stride], d = x4[i + 3 * stride];
        acc4(a, mn, mx, s, ss, nz);
        acc4(b, mn, mx, s, ss, nz);
        acc4(c, mn, mx, s, ss, nz);
        acc4(d, mn, mx, s, ss, nz);
    }
    for (; i < n4; i += stride) acc4(x4[i], mn, mx, s, ss, nz);
    if (blockIdx.x == 0 && threadIdx.x < (int)(n & 3)) {  // scalar tail
        float v = x[(n4 << 2) + threadIdx.x];
        mn = fminf(mn, v); mx = fmaxf(mx, v);
        s += v; ss += v * v; nz += (v != 0.f);
    }

    // wave(64) reduce
    double sd = (double)s, ssd = (double)ss;
    #pragma unroll
    for (int off = 32; off > 0; off >>= 1) {
        mn = fminf(mn, __shfl_down(mn, off));
        mx = fmaxf(mx, __shfl_down(mx, off));
        sd  += __shfl_down(sd, off);
        ssd += __shfl_down(ssd, off);
        nz  += __shfl_down(nz, off);
    }
    __shared__ float lmn[4], lmx[4];
    __shared__ double lsum[4], lss[4];
    __shared__ unsigned int lnz[4];
    int w = threadIdx.x >> 6;
    if ((threadIdx.x & 63) == 0) { lmn[w] = mn; lmx[w] = mx; lsum[w] = sd; lss[w] = ssd; lnz[w] = nz; }
    __syncthreads();
    if (threadIdx.x == 0) {
        Partial p;
        p.mnk = fkey(fminf(fminf(lmn[0], lmn[1]), fminf(lmn[2], lmn[3])));
        p.mxk = fkey(fmaxf(fmaxf(lmx[0], lmx[1]), fmaxf(lmx[2], lmx[3])));
        p.nz  = lnz[0] + lnz[1] + lnz[2] + lnz[3];
        p.pad = 0;
        p.s  = lsum[0] + lsum[1] + lsum[2] + lsum[3];
        p.ss = lss[0] + lss[1] + lss[2] + lss[3];
        part[blockIdx.x] = p;
    }
}

__global__ void __launch_bounds__(256) k_mid(const Partial* __restrict__ part,
                                             Finals* __restrict__ fin) {
    unsigned int mnk = 0xFFFFFFFFu, mxk = 0u;
    unsigned long long nz = 0ull;
    double s = 0.0, ss = 0.0;
    for (int i = threadIdx.x; i < NB1; i += 256) {
        Partial p = part[i];
        mnk = min(mnk, p.mnk); mxk = max(mxk, p.mxk);
        nz += p.nz; s += p.s; ss += p.ss;
    }
    #pragma unroll
    for (int off = 32; off > 0; off >>= 1) {
        mnk = min(mnk, __shfl_down(mnk, off));
        mxk = max(mxk, __shfl_down(mxk, off));
        nz += __shfl_down(nz, off);
        s  += __shfl_down(s, off);
        ss += __shfl_down(ss, off);
    }
    __shared__ unsigned int la[4], lb[4];
    __shared__ unsigned long long lnz[4];
    __shared__ double ls[4], lss[4];
    int w = threadIdx.x >> 6;
    if ((threadIdx.x & 63) == 0) { la[w] = mnk; lb[w] = mxk; lnz[w] = nz; ls[w] = s; lss[w] = ss; }
    __syncthreads();
    if (threadIdx.x == 0) {
        fin->minkey = min(min(la[0], la[1]), min(la[2], la[3]));
        fin->maxkey = max(max(lb[0], lb[1]), max(lb[2], lb[3]));
        fin->nz  = lnz[0] + lnz[1] + lnz[2] + lnz[3];
        fin->sum = ls[0] + ls[1] + ls[2] + ls[3];
        fin->ss  = lss[0] + lss[1] + lss[2] + lss[3];
    }
}

__device__ __forceinline__ void bump(float v, float mn, float step, float inv,
                                     unsigned int* hist, int tid) {
    int b = (int)((v - mn) * inv);
    b = b < 0 ? 0 : (b > NBINS - 1 ? NBINS - 1 : b);
    // exact fixup vs emitted edges (searchsorted side="right" - 1, last bin inclusive)
    while (b > 0 && v < edge_at(mn, step, b)) --b;
    while (b < NBINS - 1 && v >= edge_at(mn, step, b + 1)) ++b;
    atomicAdd(&hist[b * PITCH + tid], 1u);
}

__global__ void __launch_bounds__(256) k_hist(const float* __restrict__ x, long long n,
                                              const Finals* __restrict__ fin,
                                              unsigned int* __restrict__ cpart) {
    __shared__ unsigned int hist[NBINS * PITCH];
    int tid = threadIdx.x;
    for (int j = tid; j < NBINS * PITCH; j += 256) hist[j] = 0u;

    float mn = funkey(fin->minkey);
    float mx = funkey(fin->maxkey);
    float step = (mx - mn) / 31.0f;
    float inv  = 31.0f / (mx - mn);
    __syncthreads();

    long long n4 = n >> 2;
    const float4* __restrict__ x4 = (const float4*)x;
    long long stride = (long long)gridDim.x * blockDim.x;
    long long i = (long long)blockIdx.x * blockDim.x + tid;
    for (; i + stride < n4; i += 2 * stride) {
        float4 a = x4[i], b = x4[i + stride];
        bump(a.x, mn, step, inv, hist, tid); bump(a.y, mn, step, inv, hist, tid);
        bump(a.z, mn, step, inv, hist, tid); bump(a.w, mn, step, inv, hist, tid);
        bump(b.x, mn, step, inv, hist, tid); bump(b.y, mn, step, inv, hist, tid);
        bump(b.z, mn, step, inv, hist, tid); bump(b.w, mn, step, inv, hist, tid);
    }
    for (; i < n4; i += stride) {
        float4 a = x4[i];
        bump(a.x, mn, step, inv, hist, tid); bump(a.y, mn, step, inv, hist, tid);
        bump(a.z, mn, step, inv, hist, tid); bump(a.w, mn, step, inv, hist, tid);
    }
    if (blockIdx.x == 0 && tid < (int)(n & 3))
        bump(x[(n4 << 2) + tid], mn, step, inv, hist, tid);
    __syncthreads();

    // block reduce: wave w handles bins b = w, w+4, ...; plain store of per-block count
    int w = tid >> 6, lane = tid & 63;
    for (int b = w; b < NBINS; b += 4) {
        const unsigned int* row = &hist[b * PITCH];
        uint4 q = *(const uint4*)(row + (lane << 2));
        unsigned int sv = q.x + q.y + q.z + q.w;
        #pragma unroll
        for (int off = 32; off > 0; off >>= 1) sv += __shfl_down(sv, off);
        if (lane == 0) cpart[b * NB2 + blockIdx.x] = sv;
    }
}

__global__ void __launch_bounds__(256) k_final(const Finals* __restrict__ fin,
                                               const unsigned int* __restrict__ cpart,
                                               float* __restrict__ out, long long n) {
    float mn = funkey(fin->minkey);
    float mx = funkey(fin->maxkey);
    float step = (mx - mn) / 31.0f;
    int w = threadIdx.x >> 6, lane = threadIdx.x & 63;
    for (int b = w; b < NBINS; b += 4) {                  // reduce cpart[b][0..NB2)
        unsigned int sv = 0;
        for (int k = lane; k < NB2; k += 64) sv += cpart[b * NB2 + k];
        #pragma unroll
        for (int off = 32; off > 0; off >>= 1) sv += __shfl_down(sv, off);
        if (lane == 0) out[6 + b] = (float)sv;
    }
    int t = threadIdx.x;
    if (t == 0) {
        out[0] = mn;
        out[1] = mx;
        out[2] = (float)n;
        out[3] = (float)fin->nz;
        out[4] = (float)fin->sum;
        out[5] = (float)fin->ss;
    }
    if (t < NBINS + 1) out[6 + NBINS + t] = (t == NBINS) ? mx : edge_at(mn, step, t);
}

extern "C" void kernel_launch(void* const* d_in, const int* in_sizes, int n_in,
                              void* d_out, int out_size, void* d_ws, size_t ws_size,
                              hipStream_t stream) {
    const float* x = (const float*)d_in[0];
    long long n = (long long)in_sizes[0];
    char* ws = (char*)d_ws;
    Partial* part = (Partial*)ws;
    Finals* fin = (Finals*)(ws + OFF_F);
    unsigned int* cpart = (unsigned int*)(ws + OFF_C);
    float* out = (float*)d_out;

    k_reduce<<<dim3(NB1), dim3(256), 0, stream>>>(x, n, part);
    k_mid<<<dim3(1), dim3(256), 0, stream>>>(part, fin);
    k_hist<<<dim3(NB2), dim3(256), 0, stream>>>(x, n, fin, cpart);
    k_final<<<dim3(1), dim3(256), 0, stream>>>(fin, cpart, out, n);
}

// Round 3
// 421.454 us; speedup vs baseline: 2.8253x; 1.2801x over previous
//
#include <hip/hip_runtime.h>

#define NBINS 31
#define NB1 2048   // k_reduce grid
#define NB2 1024   // k_hist grid
#define PITCH 256  // words per hist row: atomic bank = (256b+tid)%32 = tid%32 -> 2-way (free)

struct Partial {                       // 32 B, one per k_reduce block
    unsigned int mnk, mxk, nz, pad;
    double s, ss;
};
struct Finals {
    unsigned int minkey, maxkey;
    unsigned long long nz;
    double sum, ss;
};
// ws layout:
//   [0, NB1*32)                  Partial part[NB1]            (64 KB)
//   [OFF_F, OFF_F+64)            Finals                       (64 B)
//   [OFF_C, OFF_C+NBINS*NB2*4)   unsigned cpart[NBINS][NB2]   (124 KB)
#define OFF_F (NB1 * 32)
#define OFF_C (OFF_F + 64)

__device__ __forceinline__ unsigned int fkey(float f) {
    unsigned int u = __float_as_uint(f);
    return (u & 0x80000000u) ? ~u : (u | 0x80000000u);
}
__device__ __forceinline__ float funkey(unsigned int k) {
    return (k & 0x80000000u) ? __uint_as_float(k & 0x7FFFFFFFu)
                             : __uint_as_float(~k);
}
// Must match edges emitted in k_final exactly: mul then add, no FMA contraction.
__device__ __forceinline__ float edge_at(float mn, float step, int i) {
    return __fadd_rn(mn, __fmul_rn((float)i, step));
}

__device__ __forceinline__ void acc4(float4 v, float& mn, float& mx, float& s, float& ss,
                                     unsigned int& nz) {
    mn = fminf(mn, fminf(fminf(v.x, v.y), fminf(v.z, v.w)));
    mx = fmaxf(mx, fmaxf(fmaxf(v.x, v.y), fmaxf(v.z, v.w)));
    s  += (v.x + v.y) + (v.z + v.w);
    ss += (v.x * v.x + v.y * v.y) + (v.z * v.z + v.w * v.w);
    nz += (v.x != 0.f) + (v.y != 0.f) + (v.z != 0.f) + (v.w != 0.f);
}

__global__ void __launch_bounds__(256) k_reduce(const float* __restrict__ x, long long n,
                                                Partial* __restrict__ part) {
    long long n4 = n >> 2;
    const float4* __restrict__ x4 = (const float4*)x;
    float mn = INFINITY, mx = -INFINITY, s = 0.f, ss = 0.f;
    unsigned int nz = 0u;

    long long stride = (long long)gridDim.x * blockDim.x;
    long long i = (long long)blockIdx.x * blockDim.x + threadIdx.x;
    for (; i + 3 * stride < n4; i += 4 * stride) {       // 4 independent loads in flight
        float4 a = x4[i], b = x4[i + stride], c = x4[i + 2 * stride], d = x4[i + 3 * stride];
        acc4(a, mn, mx, s, ss, nz);
        acc4(b, mn, mx, s, ss, nz);
        acc4(c, mn, mx, s, ss, nz);
        acc4(d, mn, mx, s, ss, nz);
    }
    for (; i < n4; i += stride) acc4(x4[i], mn, mx, s, ss, nz);
    if (blockIdx.x == 0 && threadIdx.x < (int)(n & 3)) {  // scalar tail
        float v = x[(n4 << 2) + threadIdx.x];
        mn = fminf(mn, v); mx = fmaxf(mx, v);
        s += v; ss += v * v; nz += (v != 0.f);
    }

    // wave(64) reduce
    double sd = (double)s, ssd = (double)ss;
    #pragma unroll
    for (int off = 32; off > 0; off >>= 1) {
        mn = fminf(mn, __shfl_down(mn, off));
        mx = fmaxf(mx, __shfl_down(mx, off));
        sd  += __shfl_down(sd, off);
        ssd += __shfl_down(ssd, off);
        nz  += __shfl_down(nz, off);
    }
    __shared__ float lmn[4], lmx[4];
    __shared__ double lsum[4], lss[4];
    __shared__ unsigned int lnz[4];
    int w = threadIdx.x >> 6;
    if ((threadIdx.x & 63) == 0) { lmn[w] = mn; lmx[w] = mx; lsum[w] = sd; lss[w] = ssd; lnz[w] = nz; }
    __syncthreads();
    if (threadIdx.x == 0) {
        Partial p;
        p.mnk = fkey(fminf(fminf(lmn[0], lmn[1]), fminf(lmn[2], lmn[3])));
        p.mxk = fkey(fmaxf(fmaxf(lmx[0], lmx[1]), fmaxf(lmx[2], lmx[3])));
        p.nz  = lnz[0] + lnz[1] + lnz[2] + lnz[3];
        p.pad = 0;
        p.s  = lsum[0] + lsum[1] + lsum[2] + lsum[3];
        p.ss = lss[0] + lss[1] + lss[2] + lss[3];
        part[blockIdx.x] = p;
    }
}

__global__ void __launch_bounds__(256) k_mid(const Partial* __restrict__ part,
                                             Finals* __restrict__ fin) {
    unsigned int mnk = 0xFFFFFFFFu, mxk = 0u;
    unsigned long long nz = 0ull;
    double s = 0.0, ss = 0.0;
    for (int i = threadIdx.x; i < NB1; i += 256) {
        Partial p = part[i];
        mnk = min(mnk, p.mnk); mxk = max(mxk, p.mxk);
        nz += p.nz; s += p.s; ss += p.ss;
    }
    #pragma unroll
    for (int off = 32; off > 0; off >>= 1) {
        mnk = min(mnk, __shfl_down(mnk, off));
        mxk = max(mxk, __shfl_down(mxk, off));
        nz += __shfl_down(nz, off);
        s  += __shfl_down(s, off);
        ss += __shfl_down(ss, off);
    }
    __shared__ unsigned int la[4], lb[4];
    __shared__ unsigned long long lnz[4];
    __shared__ double ls[4], lss[4];
    int w = threadIdx.x >> 6;
    if ((threadIdx.x & 63) == 0) { la[w] = mnk; lb[w] = mxk; lnz[w] = nz; ls[w] = s; lss[w] = ss; }
    __syncthreads();
    if (threadIdx.x == 0) {
        fin->minkey = min(min(la[0], la[1]), min(la[2], la[3]));
        fin->maxkey = max(max(lb[0], lb[1]), max(lb[2], lb[3]));
        fin->nz  = lnz[0] + lnz[1] + lnz[2] + lnz[3];
        fin->sum = ls[0] + ls[1] + ls[2] + ls[3];
        fin->ss  = lss[0] + lss[1] + lss[2] + lss[3];
    }
}

// Branchless exact bin: estimate is within +-1 of truth (fp error ~1e-5 bin widths),
// single fixup against the LDS edge table, then clamp.
__device__ __forceinline__ void bump(float v, float mn, float inv,
                                     const float* __restrict__ E,
                                     unsigned int* __restrict__ hist, int tid) {
    int b = (int)((v - mn) * inv);
    b = b > 30 ? 30 : b;                 // (v-mn)>=0 so b>=0 already
    float lo = E[b];
    float hi = E[b + 1];
    b += (v >= hi);
    b -= (v < lo);
    b = b > 30 ? 30 : b;                 // v==mx -> E[31]=mx hit -> clamp back
    atomicAdd(&hist[(b << 8) + tid], 1u);
}

__global__ void __launch_bounds__(256) k_hist(const float* __restrict__ x, long long n,
                                              const Finals* __restrict__ fin,
                                              unsigned int* __restrict__ cpart) {
    __shared__ unsigned int hist[NBINS * PITCH];
    __shared__ float E[NBINS + 1];
    int tid = threadIdx.x;
    for (int j = tid; j < NBINS * PITCH; j += 256) hist[j] = 0u;

    float mn = funkey(fin->minkey);
    float mx = funkey(fin->maxkey);
    float step = (mx - mn) / 31.0f;
    float inv  = 31.0f / (mx - mn);
    if (tid < NBINS + 1) E[tid] = (tid == NBINS) ? mx : edge_at(mn, step, tid);
    __syncthreads();

    long long n4 = n >> 2;
    const float4* __restrict__ x4 = (const float4*)x;
    long long stride = (long long)gridDim.x * blockDim.x;
    long long i = (long long)blockIdx.x * blockDim.x + tid;
    for (; i + stride < n4; i += 2 * stride) {
        float4 a = x4[i], b = x4[i + stride];
        bump(a.x, mn, inv, E, hist, tid); bump(a.y, mn, inv, E, hist, tid);
        bump(a.z, mn, inv, E, hist, tid); bump(a.w, mn, inv, E, hist, tid);
        bump(b.x, mn, inv, E, hist, tid); bump(b.y, mn, inv, E, hist, tid);
        bump(b.z, mn, inv, E, hist, tid); bump(b.w, mn, inv, E, hist, tid);
    }
    for (; i < n4; i += stride) {
        float4 a = x4[i];
        bump(a.x, mn, inv, E, hist, tid); bump(a.y, mn, inv, E, hist, tid);
        bump(a.z, mn, inv, E, hist, tid); bump(a.w, mn, inv, E, hist, tid);
    }
    if (blockIdx.x == 0 && tid < (int)(n & 3))
        bump(x[(n4 << 2) + tid], mn, inv, E, hist, tid);
    __syncthreads();

    // block reduce: wave w handles bins b = w, w+4, ...; plain store of per-block count
    int w = tid >> 6, lane = tid & 63;
    for (int b = w; b < NBINS; b += 4) {
        const unsigned int* row = &hist[b * PITCH];
        uint4 q = *(const uint4*)(row + (lane << 2));
        unsigned int sv = q.x + q.y + q.z + q.w;
        #pragma unroll
        for (int off = 32; off > 0; off >>= 1) sv += __shfl_down(sv, off);
        if (lane == 0) cpart[b * NB2 + blockIdx.x] = sv;
    }
}

__global__ void __launch_bounds__(256) k_final(const Finals* __restrict__ fin,
                                               const unsigned int* __restrict__ cpart,
                                               float* __restrict__ out, long long n) {
    float mn = funkey(fin->minkey);
    float mx = funkey(fin->maxkey);
    float step = (mx - mn) / 31.0f;
    int w = threadIdx.x >> 6, lane = threadIdx.x & 63;
    for (int b = w; b < NBINS; b += 4) {                  // reduce cpart[b][0..NB2)
        const uint4* row = (const uint4*)(cpart + b * NB2);
        unsigned int sv = 0;
        for (int k = lane; k < NB2 / 4; k += 64) {
            uint4 q = row[k];
            sv += q.x + q.y + q.z + q.w;
        }
        #pragma unroll
        for (int off = 32; off > 0; off >>= 1) sv += __shfl_down(sv, off);
        if (lane == 0) out[6 + b] = (float)sv;
    }
    int t = threadIdx.x;
    if (t == 0) {
        out[0] = mn;
        out[1] = mx;
        out[2] = (float)n;
        out[3] = (float)fin->nz;
        out[4] = (float)fin->sum;
        out[5] = (float)fin->ss;
    }
    if (t < NBINS + 1) out[6 + NBINS + t] = (t == NBINS) ? mx : edge_at(mn, step, t);
}

extern "C" void kernel_launch(void* const* d_in, const int* in_sizes, int n_in,
                              void* d_out, int out_size, void* d_ws, size_t ws_size,
                              hipStream_t stream) {
    const float* x = (const float*)d_in[0];
    long long n = (long long)in_sizes[0];
    char* ws = (char*)d_ws;
    Partial* part = (Partial*)ws;
    Finals* fin = (Finals*)(ws + OFF_F);
    unsigned int* cpart = (unsigned int*)(ws + OFF_C);
    float* out = (float*)d_out;

    k_reduce<<<dim3(NB1), dim3(256), 0, stream>>>(x, n, part);
    k_mid<<<dim3(1), dim3(256), 0, stream>>>(part, fin);
    k_hist<<<dim3(NB2), dim3(256), 0, stream>>>(x, n, fin, cpart);
    k_final<<<dim3(1), dim3(256), 0, stream>>>(fin, cpart, out, n);
}